// Round 4
// baseline (485.443 us; speedup 1.0000x reference)
//
#include <hip/hip_runtime.h>

// Integrate-and-fire, TBN layout. One thread per 4 consecutive neurons.
// History:
//  R4 (177us, 421MB, VGPR=32): loads-only main loop + bitmask store epilogue.
//  R5 (213us): 2 cols/thread PF8 @ (256,4): BW 3.1 TB/s but traffic +55%.
//  R6 (188us): C-level PF8 ring @ (256,8): compiler collapsed it (VGPR=32).
//  R7 (193us): inline-asm ring + counted vmcnt: allocator defeated it
//      (VGPR=32, occ 61%). CONCLUSION: load-side MLP alone never beats R4.
//  R8 theory: R4 is READ-PHASE/WRITE-PHASE SERIALIZED. One cohort (2048
//      blocks all resident), every wave loads 32 planes then stores 32
//      planes -> bus sees reads, then writes, nearly disjoint in time.
//      268MB reads @ ~3.5 + 281MB writes @ ~3.5 serial = ~160us = observed.
//      Fix: chunk T into 4x8 with double-buffered loads and INLINE stores:
//      per chunk issue next-8 loads, then wait/compute/store current 8.
//      Stores sit behind newer loads in the vmcnt queue, so the compiler's
//      counted waits never drain them (unlike R1-R3's per-plane poison),
//      and R/W are continuously mixed on the bus. (256,4) = 128-VGPR
//      budget, which R5 proved the compiler actually uses (R6/R7's (256,8)
//      collapse). Grid 2048, 4 resident blocks/CU -> cohort seam overlap.

typedef float v4f __attribute__((ext_vector_type(4)));

#define T_STEPS 32
#define CH 8

__global__ __launch_bounds__(256, 4) void if_kernel(const v4f* __restrict__ x,
                                                    v4f* __restrict__ y,
                                                    int bn4) {
    int idx = blockIdx.x * blockDim.x + threadIdx.x;
    if (idx >= bn4) return;

    const v4f* xp = x + idx;
    v4f* yp = y + idx;

    float v0 = 0.f, v1 = 0.f, v2 = 0.f, v3 = 0.f;

    v4f A[CH], B[CH];   // all indices compile-time -> registers (rule #20)

#define PREFETCH(BUF, TBASE)                                                 \
    _Pragma("unroll") for (int j = 0; j < CH; ++j) {                         \
        BUF[j] = xp[(size_t)((TBASE) + j) * bn4];                            \
    }

#define IF_STEP(BUF, J, T)                                                   \
    {                                                                        \
        v4f xv = BUF[J];                                                     \
        float a0 = v0 + xv.x;                                                \
        float a1 = v1 + xv.y;                                                \
        float a2 = v2 + xv.z;                                                \
        float a3 = v3 + xv.w;                                                \
        bool s0 = a0 >= 1.0f;                                                \
        bool s1 = a1 >= 1.0f;                                                \
        bool s2 = a2 >= 1.0f;                                                \
        bool s3 = a3 >= 1.0f;                                                \
        v4f out;                                                             \
        out.x = s0 ? 1.0f : 0.0f;                                            \
        out.y = s1 ? 1.0f : 0.0f;                                            \
        out.z = s2 ? 1.0f : 0.0f;                                            \
        out.w = s3 ? 1.0f : 0.0f;                                            \
        __builtin_nontemporal_store(out, yp + (size_t)(T)*bn4);              \
        v0 = s0 ? a0 - 1.0f : a0;                                            \
        v1 = s1 ? a1 - 1.0f : a1;                                            \
        v2 = s2 ? a2 - 1.0f : a2;                                            \
        v3 = s3 ? a3 - 1.0f : a3;                                            \
    }

#define PROCESS(BUF, TBASE)                                                  \
    IF_STEP(BUF, 0, (TBASE) + 0)                                             \
    IF_STEP(BUF, 1, (TBASE) + 1)                                             \
    IF_STEP(BUF, 2, (TBASE) + 2)                                             \
    IF_STEP(BUF, 3, (TBASE) + 3)                                             \
    IF_STEP(BUF, 4, (TBASE) + 4)                                             \
    IF_STEP(BUF, 5, (TBASE) + 5)                                             \
    IF_STEP(BUF, 6, (TBASE) + 6)                                             \
    IF_STEP(BUF, 7, (TBASE) + 7)

    // Prologue: chunk 0 loads
    PREFETCH(A, 0)

    // Chunk 0: prefetch chunk 1 into B, consume A, store planes 0-7
    PREFETCH(B, CH)
    PROCESS(A, 0)

    // Chunk 1: prefetch chunk 2 into A, consume B, store planes 8-15
    PREFETCH(A, 2 * CH)
    PROCESS(B, CH)

    // Chunk 2: prefetch chunk 3 into B, consume A, store planes 16-23
    PREFETCH(B, 3 * CH)
    PROCESS(A, 2 * CH)

    // Chunk 3: consume B, store planes 24-31 (no more prefetch)
    PROCESS(B, 3 * CH)

#undef PROCESS
#undef IF_STEP
#undef PREFETCH
}

extern "C" void kernel_launch(void* const* d_in, const int* in_sizes, int n_in,
                              void* d_out, int out_size, void* d_ws, size_t ws_size,
                              hipStream_t stream) {
    const float* x = (const float*)d_in[0];
    float* y = (float*)d_out;

    int total = in_sizes[0];        // T*B*N = 67,108,864
    int bn = total / T_STEPS;       // B*N  =  2,097,152
    int bn4 = bn / 4;               //        524,288 float4 columns

    int block = 256;
    int grid = (bn4 + block - 1) / block;  // 2048 blocks; 4 resident/CU

    if_kernel<<<grid, block, 0, stream>>>((const v4f*)x, (v4f*)y, bn4);
}

// Round 5
// 474.533 us; speedup vs baseline: 1.0230x; 1.0230x over previous
//
#include <hip/hip_runtime.h>

// Integrate-and-fire, TBN layout. One thread per 4 consecutive neurons.
// History (dur / traffic / VGPR / BW):
//  R4 177us 431MB v32 2.44: loads-only loop + bitmask epilogue. Baseline.
//  R5 213us 667MB v64 3.12: 2col+PF8 @(256,4). ONLY round compiler kept
//     >32 VGPRs of loads in flight -> highest BW. Lost to traffic bloat
//     (2 interleaved store streams) + grid 1024.
//  R6 188us 509MB v32 2.70: PF8 @(256,8). Budget 64 -> ring collapsed.
//  R7 193us 455MB v32 2.35: asm ring. Allocator defeated it.
//  R8 195us 403MB v36 2.07: chunked dbuf + inline stores @(256,4). Ideal
//     traffic but ring collapsed + store-acks back in the wait chain.
//  Pattern: budget 128 -> ring honored (R5); budget 64 -> collapsed (R6/R7);
//  stores in main loop -> serialization (R1-R3, R8). Everything idle
//  (VALU<10%, HBM<40%) = under-queued latency regime.
//  R9 = the untested clean cell: budget 128 (256,4) + 1 col/thread +
//  loads-only main loop (bitmask epilogue, single nt-store stream) + PF=16
//  ring (64 data VGPRs, the shape R5 proved gets honored). Grid 2048 ->
//  4 resident blocks/CU, 2 cohorts (cohort2 loads overlap cohort1 stores).
//  Target: 16 waves/CU x 16KiB = 256 KiB in flight per CU.

typedef float v4f __attribute__((ext_vector_type(4)));

#define T_STEPS 32
#define PF 16

__global__ __launch_bounds__(256, 4) void if_kernel(const v4f* __restrict__ x,
                                                    v4f* __restrict__ y,
                                                    int bn4) {
    int idx = blockIdx.x * blockDim.x + threadIdx.x;
    if (idx >= bn4) return;

    const v4f* xp = x + idx;

    float v0 = 0.f, v1 = 0.f, v2 = 0.f, v3 = 0.f;
    unsigned m0 = 0u, m1 = 0u, m2 = 0u, m3 = 0u;

    // ---- PF=16 prefetch ring: 16 x 1 KiB per wave in flight ----
    // All indices compile-time after full unroll -> stays in registers
    // (rule #20). 64 data VGPRs; budget at (256,4) is 128.
    v4f r[PF];
#pragma unroll
    for (int j = 0; j < PF; ++j) {
        r[j] = xp[(size_t)j * bn4];
    }

    // Main loop: loads are the ONLY vmem ops here -- no store ever enters
    // the vmcnt wait chain (R4's key property, kept through R9).
#pragma unroll
    for (int t = 0; t < T_STEPS; ++t) {
        const int s = t & (PF - 1);
        v4f xv = r[s];
        if (t + PF < T_STEPS) {
            r[s] = xp[(size_t)(t + PF) * bn4];   // refill ring slot
        }

        float a0 = v0 + xv.x;
        float a1 = v1 + xv.y;
        float a2 = v2 + xv.z;
        float a3 = v3 + xv.w;
        bool s0 = a0 >= 1.0f;
        bool s1 = a1 >= 1.0f;
        bool s2 = a2 >= 1.0f;
        bool s3 = a3 >= 1.0f;
        m0 |= (unsigned)s0 << t;
        m1 |= (unsigned)s1 << t;
        m2 |= (unsigned)s2 << t;
        m3 |= (unsigned)s3 << t;
        v0 = s0 ? a0 - 1.0f : a0;   // soft reset by subtraction
        v1 = s1 ? a1 - 1.0f : a1;
        v2 = s2 ? a2 - 1.0f : a2;
        v3 = s3 ? a3 - 1.0f : a3;
    }

    // ---- Epilogue: expand bitmasks, single sequential nt-store stream ----
    // (Single stream/thread keeps WRITE_SIZE at ~1.0x ideal: R4/R5/R8 A-B.)
    v4f* yp = y + idx;
#pragma unroll
    for (int t = 0; t < T_STEPS; ++t) {
        v4f out;
        out.x = ((m0 >> t) & 1u) ? 1.0f : 0.0f;
        out.y = ((m1 >> t) & 1u) ? 1.0f : 0.0f;
        out.z = ((m2 >> t) & 1u) ? 1.0f : 0.0f;
        out.w = ((m3 >> t) & 1u) ? 1.0f : 0.0f;
        __builtin_nontemporal_store(out, yp + (size_t)t * bn4);
    }
}

extern "C" void kernel_launch(void* const* d_in, const int* in_sizes, int n_in,
                              void* d_out, int out_size, void* d_ws, size_t ws_size,
                              hipStream_t stream) {
    const float* x = (const float*)d_in[0];
    float* y = (float*)d_out;

    int total = in_sizes[0];        // T*B*N = 67,108,864
    int bn = total / T_STEPS;       // B*N  =  2,097,152
    int bn4 = bn / 4;               //        524,288 float4 columns

    int block = 256;
    int grid = (bn4 + block - 1) / block;  // 2048 blocks; 4 resident/CU

    if_kernel<<<grid, block, 0, stream>>>((const v4f*)x, (v4f*)y, bn4);
}